// Round 11
// baseline (809.529 us; speedup 1.0000x reference)
//
#include <hip/hip_runtime.h>

// FourierBlock: per (b, c): rfft(4096) -> keep top-16 |X| bins -> irfft.
//
// Round 14 = round 13 resubmitted (previous bench died to an MI355X
// container infrastructure failure; kernel audit found no OOB/race/hang).
//
// Round 13: combine the two proven wins that were never in one kernel:
//   - float4 merged I/O (round 4/7: WRITE_SIZE == 131072 KB exactly, FETCH
//     65 MB -> ~200 MB total HBM traffic) -- round 9 showed the float2
//     variant is HBM-BOUND on 1.4 GB of amplified strided traffic;
//   - high occupancy at 512 thr / 33 KB LDS (round 6 reached 84% occ with
//     this shape; rounds 6/8 proved dur ~ 1/occupancy for the latency part).
// Round 7/8 failed this combo only through VGPR spill (demand ~80 > 64 cap).
// Demand is cut structurally:
//   (1) no parked registers -- half 1 re-reads the float4 (L3-resident);
//   (2) hierarchical top-k: all 8 waves scan with m2[8] (waves 0-3 ch-even,
//       4-7 ch-odd), each wave finds its LOCAL top-16 wave-locally (no
//       barriers), writes candidates to LDS; waves 0/4 merge 64 candidates
//       -> global top-16 (total order (m2,-f) makes this exact) and capture
//       coefficients. Replaces m2[32] (32 regs) with m2[8]; barriers 42->14.
//   (3) synth stages ch0/ch1 through the dead 32 KB spectrum LDS; only
//       ch2/ch3 accumulate in registers (16) during the last two passes.
// Audited peak ~50 VGPR. __launch_bounds__(512, 2): cap 128, NO forced
// spill; round 9 showed the compiler targets <=64 when demand allows
// (occupancy heuristic), which yields 4 blocks x 8 waves = 32 waves/CU.

#define SWZ(i) ((i) ^ (((i) >> 4) & 15))

__device__ __forceinline__ int drev8(int x) {
  // reverse the four octal digits of a 12-bit index (involution)
  return ((x & 7) << 9) | ((x & 0x38) << 3) | ((x >> 3) & 0x38) | ((x >> 9) & 7);
}

__device__ __forceinline__ float2 cmulf(float2 a, float c, float s) {
  return make_float2(a.x * c - a.y * s, a.x * s + a.y * c);
}

__device__ __forceinline__ float2 cadd(float2 a, float2 b) { return make_float2(a.x + b.x, a.y + b.y); }
__device__ __forceinline__ float2 csub(float2 a, float2 b) { return make_float2(a.x - b.x, a.y - b.y); }
__device__ __forceinline__ float2 cmulnegi(float2 a) { return make_float2(a.y, -a.x); }      // a * (-i)
__device__ __forceinline__ float2 cmulposi(float2 a) { return make_float2(-a.y, a.x); }      // a * (+i)

// 8-point DFT in registers, natural-order input AND output.
__device__ __forceinline__ void dft8(float2* a) {
  const float R = 0.7071067811865476f;
  float2 t0 = cadd(a[0], a[4]), t1 = cadd(a[1], a[5]);
  float2 t2 = cadd(a[2], a[6]), t3 = cadd(a[3], a[7]);
  float2 u0 = csub(a[0], a[4]);
  float2 d1 = csub(a[1], a[5]);
  float2 u1 = make_float2(R * (d1.x + d1.y), R * (d1.y - d1.x));   // * W8^1
  float2 u2 = cmulnegi(csub(a[2], a[6]));                          // * W8^2
  float2 d3 = csub(a[3], a[7]);
  float2 u3 = make_float2(R * (d3.y - d3.x), R * (-(d3.x + d3.y))); // * W8^3
  {
    float2 b0 = cadd(t0, t2), b1 = csub(t0, t2);
    float2 b2 = cadd(t1, t3), b3 = csub(t1, t3);
    a[0] = cadd(b0, b2);
    a[2] = cadd(b1, cmulnegi(b3));
    a[4] = csub(b0, b2);
    a[6] = cadd(b1, cmulposi(b3));
  }
  {
    float2 b0 = cadd(u0, u2), b1 = csub(u0, u2);
    float2 b2 = cadd(u1, u3), b3 = csub(u1, u3);
    a[1] = cadd(b0, b2);
    a[3] = cadd(b1, cmulnegi(b3));
    a[5] = csub(b0, b2);
    a[7] = cadd(b1, cmulposi(b3));
  }
}

// One radix-8 DIF pass; twiddle W_M^{j*r}, angle j*r/M rev (exact fp32,
// in [0,1)) -> v_sin/v_cos. M=8: last pass, no twiddle.
template <int STRIDE, int M>
__device__ __forceinline__ void fft_pass8(float2* Zl, int base, int j) {
  float2 v[8];
  #pragma unroll
  for (int p = 0; p < 8; p++) v[p] = Zl[SWZ(base + j + STRIDE * p)];
  dft8(v);
  #pragma unroll
  for (int r = 1; r < 8; r++) {
    if (M > 8) {
      int a = j * r;                                // < M
      float x = (float)a * (1.0f / (float)M);       // revolutions, exact
      float s = -__builtin_amdgcn_sinf(x);          // e^{-2 pi i x}
      float c =  __builtin_amdgcn_cosf(x);
      v[r] = cmulf(v[r], c, s);
    }
  }
  #pragma unroll
  for (int r = 0; r < 8; r++) Zl[SWZ(base + j + STRIDE * r)] = v[r];
}

// Chebyshev synthesis of ONE channel's 8 samples l = tid + 512k from the 16
// bins at CF[cbase..]. g(l+512) = T g(l) - g(l-512), T = 2 cos(2 pi f/8).
// Seeds x0 = f*tid/4096 rev exact (f*tid <= 2048*511 < 2^23).
__device__ __forceinline__ void synth8(const float4* CF, const float* CFf,
                                       int cbase, float tf, float* acc) {
  #pragma unroll
  for (int k = 0; k < 8; k++) acc[k] = 0.f;
  #pragma unroll 1
  for (int g = 0; g < 4; g++) {
    float u[4], v[4], T[4];
    #pragma unroll
    for (int j = 0; j < 4; j++) {
      float4 cf = CF[cbase + g * 4 + j];
      float f  = CFf[cbase + g * 4 + j];
      float x0 = f * tf * 2.44140625e-4f;
      x0 -= floorf(x0);
      float c0 = __builtin_amdgcn_cosf(x0);
      float s0 = __builtin_amdgcn_sinf(x0);
      float G = fmaf(cf.x, c0, cf.y * s0);    // g(tid)
      float H = fmaf(cf.y, c0, -cf.x * s0);   // b cos - a sin
      u[j] = G;
      v[j] = fmaf(G, cf.z, -H * cf.w);        // g(tid - 512)
      T[j] = cf.z + cf.z;
    }
    #pragma unroll
    for (int k = 0; k < 8; k += 2) {
      #pragma unroll
      for (int j = 0; j < 4; j++) { acc[k] += u[j];     v[j] = fmaf(T[j], u[j], -v[j]); }
      #pragma unroll
      for (int j = 0; j < 4; j++) { acc[k + 1] += v[j]; u[j] = fmaf(T[j], v[j], -u[j]); }
    }
  }
}

// ---------------- fused FFT + top-k + synthesis kernel ---------------------

__global__ __launch_bounds__(512, 2) void fourier_fused(
    const float4* __restrict__ X4, float4* __restrict__ O4) {
  __shared__ float2 Z[4096];        // one 4096-pt complex workspace (32 KB)
  __shared__ float4 CF[64];         // [gc*16+r] = (alpha, beta, cos_st, sin_st)
  __shared__ float  CFf[64];        // bin frequency f
  __shared__ float2 CAND[128];      // 8 waves x 16 local-top candidates

  const int tid = threadIdx.x;
  const int wv = tid >> 6;          // wave 0..7
  const int lane = tid & 63;
  // XCD-contiguous remap (bijective: 2048 blocks, 8 XCDs, 256 each):
  // 8 whole batches per XCD -> the 32 sibling blocks of a batch run on one
  // XCD and merge their strided float4 reads/writes in that XCD's L2.
  const int o = ((blockIdx.x & 7) << 8) + (blockIdx.x >> 3);
  const int b = o >> 5;
  const int q = o & 31;             // 4-channel group: channels 4q..4q+3

  const float inv = 2.44140625e-4f; // 1/4096
  const float4* src = X4 + (size_t)b * 4096 * 32 + q;

  // ---- two sequential {load, FFT, top-k} halves over the same Z ----
  #pragma unroll 1
  for (int half = 0; half < 2; half++) {
    // load channel pair of this half (half 1 re-reads the same float4;
    // L3-resident, no registers parked across phases)
    #pragma unroll
    for (int k = 0; k < 8; k++) {
      int l = tid + 512 * k;
      float4 v = src[(size_t)l * 32];
      Z[SWZ(l)] = half ? make_float2(v.z, v.w) : make_float2(v.x, v.y);
    }
    __syncthreads();

    // forward FFT: 4 radix-8 DIF passes; slot p ends holding bin drev8(p)
    fft_pass8<512, 4096>(Z, 0, tid);
    __syncthreads();
    fft_pass8<64, 512>(Z, (tid >> 6) << 9, tid & 63);
    __syncthreads();
    fft_pass8<8, 64>(Z, (tid >> 3) << 6, tid & 7);
    __syncthreads();
    fft_pass8<1, 8>(Z, tid << 3, 0);
    __syncthreads();

    // ---- scan: waves 0-3 -> even channel, waves 4-7 -> odd channel.
    // Wave wq of a channel covers f = lane + 64*(8*wq + k), k<8 (0..2047).
    const int ch = wv >> 2;
    const int wq = wv & 3;
    float m2[8];
    #pragma unroll
    for (int k = 0; k < 8; k++) {
      int f = lane + ((wq * 8 + k) << 6);
      float2 P = Z[SWZ(drev8(f))];
      float2 Q = Z[SWZ(drev8((4096 - f) & 4095))];
      float xr = ch ? (P.y + Q.y) : (P.x + Q.x);
      float xi = ch ? (Q.x - P.x) : (P.y - Q.y);
      m2[k] = xr * xr + xi * xi;   // 4*|X|^2 (ordering only)
    }
    float m2x = -1.f;              // Nyquist f=2048: wq==0, lane 0 only
    if (wq == 0 && lane == 0) {
      float2 P = Z[SWZ(4)];        // drev8(2048) == 4
      float t = ch ? P.y : P.x;
      m2x = 4.f * t * t;
    }

    // ---- wave-local top-16 (no barriers); lane r keeps round-r winner ----
    float cbv = -1.f; int cbf = 0;
    for (int r = 0; r < 16; r++) {
      float bv = -1e30f; int bf = 0;
      #pragma unroll
      for (int k = 0; k < 8; k++) {
        int f = lane + ((wq * 8 + k) << 6);
        if (m2[k] > bv) { bv = m2[k]; bf = f; }   // ascending: ties -> lower f
      }
      if (m2x > bv) { bv = m2x; bf = 2048; }
      #pragma unroll
      for (int off = 32; off; off >>= 1) {
        float ov = __shfl_down(bv, off);
        int   of = __shfl_down(bf, off);
        if (ov > bv || (ov == bv && of < bf)) { bv = ov; bf = of; }
      }
      bv = __shfl(bv, 0);
      bf = __shfl(bf, 0);
      if (lane == r) { cbv = bv; cbf = bf; }
      if (bf == 2048) {                          // knockout
        if (wq == 0 && lane == 0) m2x = -2.f;
      } else if ((bf & 63) == lane) {
        int kk = (bf >> 6) - 8 * wq;             // in [0,8) for owner wave
        #pragma unroll
        for (int k = 0; k < 8; k++) if (k == kk) m2[k] = -2.f;
      }
    }
    if (lane < 16) CAND[wv * 16 + lane] = make_float2(cbv, __int_as_float(cbf));
    __syncthreads();

    // ---- merge (waves 0 and 4): 64 candidates -> global top-16 + capture.
    // Total order (m2, -f) makes the hierarchical result exactly global.
    if (wq == 0) {
      float mv = CAND[(ch << 6) + lane].x;
      int   mf = __float_as_int(CAND[(ch << 6) + lane].y);
      for (int r = 0; r < 16; r++) {
        float bv = mv; int bf = mf;
        #pragma unroll
        for (int off = 32; off; off >>= 1) {
          float ov = __shfl_down(bv, off);
          int   of = __shfl_down(bf, off);
          if (ov > bv || (ov == bv && of < bf)) { bv = ov; bf = of; }
        }
        bf = __shfl(bf, 0);
        if (lane == r) {                         // capture coefficients
          float fv = (float)bf;
          float2 P = Z[SWZ(drev8(bf))];
          float2 Q = Z[SWZ(drev8((4096 - bf) & 4095))];
          float rA = ch ? 0.5f * (P.y + Q.y) : 0.5f * (P.x + Q.x);
          float rB = ch ? 0.5f * (Q.x - P.x) : 0.5f * (P.y - Q.y);
          float w = (bf == 0 || bf == 2048) ? inv : 2.f * inv;
          float dx = fv * 0.125f;                // f*512/4096 = f/8 rev
          dx -= floorf(dx);
          float cd = __builtin_amdgcn_cosf(dx);
          float sd = __builtin_amdgcn_sinf(dx);
          int gc = half * 2 + ch;                // block channel 0..3
          CF[gc * 16 + r] = make_float4(w * rA, -w * rB, cd, sd);
          CFf[gc * 16 + r] = fv;
        }
        if (mf == bf) mv = -2.f;                 // knockout (f unique in pool)
      }
    }
    __syncthreads();   // Z consumed; CF[2*half .. ] published
  }

  // ---- synthesis: 8 samples/thread/channel; ch0/ch1 staged through the
  // dead spectrum LDS (same-thread addresses, no barrier), ch2/ch3 in regs.
  float* Zf = (float*)Z;              // 8192 floats
  float acc[8], acc2[8], acc3[8];
  const float tf = (float)tid;
  synth8(CF, CFf, 0, tf, acc);
  #pragma unroll
  for (int k = 0; k < 8; k++) Zf[tid + 512 * k] = acc[k];
  synth8(CF, CFf, 16, tf, acc);
  #pragma unroll
  for (int k = 0; k < 8; k++) Zf[4096 + tid + 512 * k] = acc[k];
  synth8(CF, CFf, 32, tf, acc2);
  synth8(CF, CFf, 48, tf, acc3);

  // ---- store: float4 = 4 channels at one sample, sibling-merged lines ----
  float4* dst = O4 + (size_t)b * 4096 * 32 + q;
  #pragma unroll
  for (int k = 0; k < 8; k++) {
    int l = tid + 512 * k;
    dst[(size_t)l * 32] = make_float4(Zf[l], Zf[4096 + l], acc2[k], acc3[k]);
  }
}

extern "C" void kernel_launch(void* const* d_in, const int* in_sizes, int n_in,
                              void* d_out, int out_size, void* d_ws, size_t ws_size,
                              hipStream_t stream) {
  (void)in_sizes; (void)n_in; (void)ws_size; (void)out_size; (void)d_ws;
  const float4* x = (const float4*)d_in[0];
  float4* out = (float4*)d_out;

  fourier_fused<<<dim3(64 * 32), dim3(512), 0, stream>>>(x, out);
}

// Round 12
// 749.426 us; speedup vs baseline: 1.0802x; 1.0802x over previous
//
#include <hip/hip_runtime.h>

// FourierBlock: per (b, c): rfft(4096) -> keep top-16 |X| bins -> irfft.
//
// Round 15 = round 13/14 structure with ONE change: __launch_bounds__(512,4)
// (was (512,2)). Round-14 counters proved the structure right: FETCH 65.7 MB
// + WRITE exactly 131072 KB (float4 sibling-merge, zero scratch). But the
// (512,2) 128-VGPR budget let the allocator CHOOSE 116 regs (scheduling
// aggressiveness, not demand) -> 4 waves/SIMD -> occ 23% -> 675 us. The
// dur*occ law (rounds 6/8/11) says occupancy is the lever. Forcing the
// 64-VGPR cap gives 8 waves/SIMD; LDS 35 KB gives 4 blocks/CU; both = 32
// waves/CU. Unlike round 7 (which spilled at this cap), minimal live state
// here is ~50-55: m2[8] hierarchical top-k (not m2[32]), no parked regs
// (half 1 re-reads the L3-resident float4), per-channel synth staged
// through dead spectrum LDS (not acc[8][4]).

#define SWZ(i) ((i) ^ (((i) >> 4) & 15))

__device__ __forceinline__ int drev8(int x) {
  // reverse the four octal digits of a 12-bit index (involution)
  return ((x & 7) << 9) | ((x & 0x38) << 3) | ((x >> 3) & 0x38) | ((x >> 9) & 7);
}

__device__ __forceinline__ float2 cmulf(float2 a, float c, float s) {
  return make_float2(a.x * c - a.y * s, a.x * s + a.y * c);
}

__device__ __forceinline__ float2 cadd(float2 a, float2 b) { return make_float2(a.x + b.x, a.y + b.y); }
__device__ __forceinline__ float2 csub(float2 a, float2 b) { return make_float2(a.x - b.x, a.y - b.y); }
__device__ __forceinline__ float2 cmulnegi(float2 a) { return make_float2(a.y, -a.x); }      // a * (-i)
__device__ __forceinline__ float2 cmulposi(float2 a) { return make_float2(-a.y, a.x); }      // a * (+i)

// 8-point DFT in registers, natural-order input AND output.
__device__ __forceinline__ void dft8(float2* a) {
  const float R = 0.7071067811865476f;
  float2 t0 = cadd(a[0], a[4]), t1 = cadd(a[1], a[5]);
  float2 t2 = cadd(a[2], a[6]), t3 = cadd(a[3], a[7]);
  float2 u0 = csub(a[0], a[4]);
  float2 d1 = csub(a[1], a[5]);
  float2 u1 = make_float2(R * (d1.x + d1.y), R * (d1.y - d1.x));   // * W8^1
  float2 u2 = cmulnegi(csub(a[2], a[6]));                          // * W8^2
  float2 d3 = csub(a[3], a[7]);
  float2 u3 = make_float2(R * (d3.y - d3.x), R * (-(d3.x + d3.y))); // * W8^3
  {
    float2 b0 = cadd(t0, t2), b1 = csub(t0, t2);
    float2 b2 = cadd(t1, t3), b3 = csub(t1, t3);
    a[0] = cadd(b0, b2);
    a[2] = cadd(b1, cmulnegi(b3));
    a[4] = csub(b0, b2);
    a[6] = cadd(b1, cmulposi(b3));
  }
  {
    float2 b0 = cadd(u0, u2), b1 = csub(u0, u2);
    float2 b2 = cadd(u1, u3), b3 = csub(u1, u3);
    a[1] = cadd(b0, b2);
    a[3] = cadd(b1, cmulnegi(b3));
    a[5] = csub(b0, b2);
    a[7] = cadd(b1, cmulposi(b3));
  }
}

// One radix-8 DIF pass; twiddle W_M^{j*r}, angle j*r/M rev (exact fp32,
// in [0,1)) -> v_sin/v_cos. M=8: last pass, no twiddle.
template <int STRIDE, int M>
__device__ __forceinline__ void fft_pass8(float2* Zl, int base, int j) {
  float2 v[8];
  #pragma unroll
  for (int p = 0; p < 8; p++) v[p] = Zl[SWZ(base + j + STRIDE * p)];
  dft8(v);
  #pragma unroll
  for (int r = 1; r < 8; r++) {
    if (M > 8) {
      int a = j * r;                                // < M
      float x = (float)a * (1.0f / (float)M);       // revolutions, exact
      float s = -__builtin_amdgcn_sinf(x);          // e^{-2 pi i x}
      float c =  __builtin_amdgcn_cosf(x);
      v[r] = cmulf(v[r], c, s);
    }
  }
  #pragma unroll
  for (int r = 0; r < 8; r++) Zl[SWZ(base + j + STRIDE * r)] = v[r];
}

// Chebyshev synthesis of ONE channel's 8 samples l = tid + 512k from the 16
// bins at CF[cbase..]. g(l+512) = T g(l) - g(l-512), T = 2 cos(2 pi f/8).
// Seeds x0 = f*tid/4096 rev exact (f*tid <= 2048*511 < 2^23).
__device__ __forceinline__ void synth8(const float4* CF, const float* CFf,
                                       int cbase, float tf, float* acc) {
  #pragma unroll
  for (int k = 0; k < 8; k++) acc[k] = 0.f;
  #pragma unroll 1
  for (int g = 0; g < 4; g++) {
    float u[4], v[4], T[4];
    #pragma unroll
    for (int j = 0; j < 4; j++) {
      float4 cf = CF[cbase + g * 4 + j];
      float f  = CFf[cbase + g * 4 + j];
      float x0 = f * tf * 2.44140625e-4f;
      x0 -= floorf(x0);
      float c0 = __builtin_amdgcn_cosf(x0);
      float s0 = __builtin_amdgcn_sinf(x0);
      float G = fmaf(cf.x, c0, cf.y * s0);    // g(tid)
      float H = fmaf(cf.y, c0, -cf.x * s0);   // b cos - a sin
      u[j] = G;
      v[j] = fmaf(G, cf.z, -H * cf.w);        // g(tid - 512)
      T[j] = cf.z + cf.z;
    }
    #pragma unroll
    for (int k = 0; k < 8; k += 2) {
      #pragma unroll
      for (int j = 0; j < 4; j++) { acc[k] += u[j];     v[j] = fmaf(T[j], u[j], -v[j]); }
      #pragma unroll
      for (int j = 0; j < 4; j++) { acc[k + 1] += v[j]; u[j] = fmaf(T[j], v[j], -u[j]); }
    }
  }
}

// ---------------- fused FFT + top-k + synthesis kernel ---------------------

__global__ __launch_bounds__(512, 4) void fourier_fused(
    const float4* __restrict__ X4, float4* __restrict__ O4) {
  __shared__ float2 Z[4096];        // one 4096-pt complex workspace (32 KB)
  __shared__ float4 CF[64];         // [gc*16+r] = (alpha, beta, cos_st, sin_st)
  __shared__ float  CFf[64];        // bin frequency f
  __shared__ float2 CAND[128];      // 8 waves x 16 local-top candidates

  const int tid = threadIdx.x;
  const int wv = tid >> 6;          // wave 0..7
  const int lane = tid & 63;
  // XCD-contiguous remap (bijective: 2048 blocks, 8 XCDs, 256 each):
  // 8 whole batches per XCD -> the 32 sibling blocks of a batch run on one
  // XCD and merge their strided float4 reads/writes in that XCD's L2.
  const int o = ((blockIdx.x & 7) << 8) + (blockIdx.x >> 3);
  const int b = o >> 5;
  const int q = o & 31;             // 4-channel group: channels 4q..4q+3

  const float inv = 2.44140625e-4f; // 1/4096
  const float4* src = X4 + (size_t)b * 4096 * 32 + q;

  // ---- two sequential {load, FFT, top-k} halves over the same Z ----
  #pragma unroll 1
  for (int half = 0; half < 2; half++) {
    // load channel pair of this half (half 1 re-reads the same float4;
    // L3-resident, no registers parked across phases)
    #pragma unroll
    for (int k = 0; k < 8; k++) {
      int l = tid + 512 * k;
      float4 v = src[(size_t)l * 32];
      Z[SWZ(l)] = half ? make_float2(v.z, v.w) : make_float2(v.x, v.y);
    }
    __syncthreads();

    // forward FFT: 4 radix-8 DIF passes; slot p ends holding bin drev8(p)
    fft_pass8<512, 4096>(Z, 0, tid);
    __syncthreads();
    fft_pass8<64, 512>(Z, (tid >> 6) << 9, tid & 63);
    __syncthreads();
    fft_pass8<8, 64>(Z, (tid >> 3) << 6, tid & 7);
    __syncthreads();
    fft_pass8<1, 8>(Z, tid << 3, 0);
    __syncthreads();

    // ---- scan: waves 0-3 -> even channel, waves 4-7 -> odd channel.
    // Wave wq of a channel covers f = lane + 64*(8*wq + k), k<8 (0..2047).
    const int ch = wv >> 2;
    const int wq = wv & 3;
    float m2[8];
    #pragma unroll
    for (int k = 0; k < 8; k++) {
      int f = lane + ((wq * 8 + k) << 6);
      float2 P = Z[SWZ(drev8(f))];
      float2 Q = Z[SWZ(drev8((4096 - f) & 4095))];
      float xr = ch ? (P.y + Q.y) : (P.x + Q.x);
      float xi = ch ? (Q.x - P.x) : (P.y - Q.y);
      m2[k] = xr * xr + xi * xi;   // 4*|X|^2 (ordering only)
    }
    float m2x = -1.f;              // Nyquist f=2048: wq==0, lane 0 only
    if (wq == 0 && lane == 0) {
      float2 P = Z[SWZ(4)];        // drev8(2048) == 4
      float t = ch ? P.y : P.x;
      m2x = 4.f * t * t;
    }

    // ---- wave-local top-16 (no barriers); lane r keeps round-r winner ----
    float cbv = -1.f; int cbf = 0;
    for (int r = 0; r < 16; r++) {
      float bv = -1e30f; int bf = 0;
      #pragma unroll
      for (int k = 0; k < 8; k++) {
        int f = lane + ((wq * 8 + k) << 6);
        if (m2[k] > bv) { bv = m2[k]; bf = f; }   // ascending: ties -> lower f
      }
      if (m2x > bv) { bv = m2x; bf = 2048; }
      #pragma unroll
      for (int off = 32; off; off >>= 1) {
        float ov = __shfl_down(bv, off);
        int   of = __shfl_down(bf, off);
        if (ov > bv || (ov == bv && of < bf)) { bv = ov; bf = of; }
      }
      bv = __shfl(bv, 0);
      bf = __shfl(bf, 0);
      if (lane == r) { cbv = bv; cbf = bf; }
      if (bf == 2048) {                          // knockout
        if (wq == 0 && lane == 0) m2x = -2.f;
      } else if ((bf & 63) == lane) {
        int kk = (bf >> 6) - 8 * wq;             // in [0,8) for owner wave
        #pragma unroll
        for (int k = 0; k < 8; k++) if (k == kk) m2[k] = -2.f;
      }
    }
    if (lane < 16) CAND[wv * 16 + lane] = make_float2(cbv, __int_as_float(cbf));
    __syncthreads();

    // ---- merge (waves 0 and 4): 64 candidates -> global top-16 + capture.
    // Total order (m2, -f) makes the hierarchical result exactly global.
    if (wq == 0) {
      float mv = CAND[(ch << 6) + lane].x;
      int   mf = __float_as_int(CAND[(ch << 6) + lane].y);
      for (int r = 0; r < 16; r++) {
        float bv = mv; int bf = mf;
        #pragma unroll
        for (int off = 32; off; off >>= 1) {
          float ov = __shfl_down(bv, off);
          int   of = __shfl_down(bf, off);
          if (ov > bv || (ov == bv && of < bf)) { bv = ov; bf = of; }
        }
        bf = __shfl(bf, 0);
        if (lane == r) {                         // capture coefficients
          float fv = (float)bf;
          float2 P = Z[SWZ(drev8(bf))];
          float2 Q = Z[SWZ(drev8((4096 - bf) & 4095))];
          float rA = ch ? 0.5f * (P.y + Q.y) : 0.5f * (P.x + Q.x);
          float rB = ch ? 0.5f * (Q.x - P.x) : 0.5f * (P.y - Q.y);
          float w = (bf == 0 || bf == 2048) ? inv : 2.f * inv;
          float dx = fv * 0.125f;                // f*512/4096 = f/8 rev
          dx -= floorf(dx);
          float cd = __builtin_amdgcn_cosf(dx);
          float sd = __builtin_amdgcn_sinf(dx);
          int gc = half * 2 + ch;                // block channel 0..3
          CF[gc * 16 + r] = make_float4(w * rA, -w * rB, cd, sd);
          CFf[gc * 16 + r] = fv;
        }
        if (mf == bf) mv = -2.f;                 // knockout (f unique in pool)
      }
    }
    __syncthreads();   // Z consumed; CF[2*half .. ] published
  }

  // ---- synthesis: 8 samples/thread/channel; ch0/ch1 staged through the
  // dead spectrum LDS (same-thread addresses, no barrier), ch2/ch3 in regs.
  float* Zf = (float*)Z;              // 8192 floats
  float acc[8], acc2[8], acc3[8];
  const float tf = (float)tid;
  synth8(CF, CFf, 0, tf, acc);
  #pragma unroll
  for (int k = 0; k < 8; k++) Zf[tid + 512 * k] = acc[k];
  synth8(CF, CFf, 16, tf, acc);
  #pragma unroll
  for (int k = 0; k < 8; k++) Zf[4096 + tid + 512 * k] = acc[k];
  synth8(CF, CFf, 32, tf, acc2);
  synth8(CF, CFf, 48, tf, acc3);

  // ---- store: float4 = 4 channels at one sample, sibling-merged lines ----
  float4* dst = O4 + (size_t)b * 4096 * 32 + q;
  #pragma unroll
  for (int k = 0; k < 8; k++) {
    int l = tid + 512 * k;
    dst[(size_t)l * 32] = make_float4(Zf[l], Zf[4096 + l], acc2[k], acc3[k]);
  }
}

extern "C" void kernel_launch(void* const* d_in, const int* in_sizes, int n_in,
                              void* d_out, int out_size, void* d_ws, size_t ws_size,
                              hipStream_t stream) {
  (void)in_sizes; (void)n_in; (void)ws_size; (void)out_size; (void)d_ws;
  const float4* x = (const float4*)d_in[0];
  float4* out = (float4*)d_out;

  fourier_fused<<<dim3(64 * 32), dim3(512), 0, stream>>>(x, out);
}